// Round 1
// baseline (457.317 us; speedup 1.0000x reference)
//
#include <hip/hip_runtime.h>
#include <math.h>

// Problem constants
// images: N = B*S = 512, each 256x256 = type[i] * token[j] (rank-1)
// stage1: conv 3x3 stride2 VALID (1->16ch) -> 127x127, GELU, pool3 -> 42x42
// stage2: conv 3x3 stride1 VALID (16->32)  -> 40x40,  GELU, pool3 -> 13x13
// stage3: conv 3x3 stride1 VALID (32->32)  -> 11x11,  GELU, pool3 -> 3x3
// out: [512][32*3*3=288] fp32

#define NIMG 512

__device__ __forceinline__ float gelu_exact(float x) {
    return 0.5f * x * (1.0f + erff(x * 0.70710678118654752f));
}

// ---------------- Kernel 1: outer-product + conv1(s2) + GELU + pool3 ----------------
// grid = NIMG*4 (4 channel-groups of 4 channels), block = 256
// s1 layout: [img][16][42][42]
__global__ __launch_bounds__(256) void k1_fused(const float* __restrict__ tok,
                                                const float* __restrict__ typ,
                                                const float* __restrict__ w1,
                                                const float* __restrict__ b1,
                                                float* __restrict__ s1) {
    const int blk = blockIdx.x;
    const int img = blk >> 2;
    const int cg  = blk & 3;                 // channels 4*cg .. 4*cg+3
    __shared__ float t[256];
    __shared__ float f[256];
    __shared__ float g[4][3][128];           // x in [0,126), padded

    const int tid = threadIdx.x;
    t[tid] = typ[img * 256 + tid];           // height axis = type_embedds
    f[tid] = tok[img * 256 + tid];           // width axis  = token_features
    __syncthreads();

    // g[c][di][x] = sum_dj w1[(4cg+c), di, dj] * f[2x+dj]
    for (int idx = tid; idx < 4 * 3 * 126; idx += 256) {
        const int x  = idx % 126;
        const int di = (idx / 126) % 3;
        const int c  = idx / (126 * 3);
        const int cc = cg * 4 + c;
        float acc = 0.f;
#pragma unroll
        for (int dj = 0; dj < 3; ++dj)
            acc += w1[cc * 9 + di * 3 + dj] * f[2 * x + dj];
        g[c][di][x] = acc;
    }
    __syncthreads();

    // pooled outputs: 4ch x 42 x 42
    for (int idx = tid; idx < 4 * 42 * 42; idx += 256) {
        const int px = idx % 42;
        const int py = (idx / 42) % 42;
        const int c  = idx / (42 * 42);
        const int cc = cg * 4 + c;
        const float bias = b1[cc];
        float m = -INFINITY;
#pragma unroll
        for (int wy = 0; wy < 3; ++wy) {
            const int y = 3 * py + wy;
            const float t0 = t[2 * y], t1 = t[2 * y + 1], t2 = t[2 * y + 2];
#pragma unroll
            for (int wx = 0; wx < 3; ++wx) {
                const int x = 3 * px + wx;
                float v = bias + t0 * g[c][0][x] + t1 * g[c][1][x] + t2 * g[c][2][x];
                v = gelu_exact(v);
                m = fmaxf(m, v);
            }
        }
        s1[((img * 16 + cc) * 42 + py) * 42 + px] = m;
    }
}

// ---------------- Kernel 2: conv2 + GELU + pool3 ----------------
// grid = NIMG*4 (4 co-groups of 8), block = 256
// s2 layout: [img][32][13][13]
__global__ __launch_bounds__(256) void k2_conv(const float* __restrict__ s1,
                                               const float* __restrict__ w2,
                                               const float* __restrict__ b2,
                                               float* __restrict__ s2) {
    const int blk = blockIdx.x;
    const int img = blk >> 2;
    const int cog = blk & 3;                 // co channels cog*8 .. cog*8+7
    __shared__ float slab[42 * 42];          // one cin plane
    __shared__ float wl[8 * 16 * 9];         // this block's weights

    const int tid = threadIdx.x;
    for (int i = tid; i < 8 * 16 * 9; i += 256) wl[i] = w2[cog * 8 * 16 * 9 + i];

    const int co   = tid >> 5;               // 0..7
    const int lane = tid & 31;

    int cell[6];
    int base[6];
#pragma unroll
    for (int tI = 0; tI < 6; ++tI) {
        cell[tI] = tI * 32 + lane;           // pooled cell id, 0..191 (169 valid)
        int c = cell[tI] > 168 ? 168 : cell[tI];
        base[tI] = (c / 13) * 3 * 42 + (c % 13) * 3;
    }

    float acc[6][9];
#pragma unroll
    for (int tI = 0; tI < 6; ++tI)
#pragma unroll
        for (int k = 0; k < 9; ++k) acc[tI][k] = 0.f;

    const float* s1img = s1 + (size_t)img * 16 * 42 * 42;

    for (int cin = 0; cin < 16; ++cin) {
        __syncthreads();                      // protect slab from previous iter
        for (int i = tid; i < 42 * 42; i += 256) slab[i] = s1img[cin * 1764 + i];
        __syncthreads();

        float w[9];
#pragma unroll
        for (int k = 0; k < 9; ++k) w[k] = wl[(co * 16 + cin) * 9 + k];

#pragma unroll
        for (int tI = 0; tI < 6; ++tI) {
            float win[5][5];
#pragma unroll
            for (int r = 0; r < 5; ++r)
#pragma unroll
                for (int c2 = 0; c2 < 5; ++c2)
                    win[r][c2] = slab[base[tI] + r * 42 + c2];
#pragma unroll
            for (int wy = 0; wy < 3; ++wy)
#pragma unroll
                for (int wx = 0; wx < 3; ++wx) {
#pragma unroll
                    for (int dy = 0; dy < 3; ++dy)
#pragma unroll
                        for (int dx = 0; dx < 3; ++dx)
                            acc[tI][wy * 3 + wx] += win[wy + dy][wx + dx] * w[dy * 3 + dx];
                }
        }
    }

    const float bias = b2[cog * 8 + co];
#pragma unroll
    for (int tI = 0; tI < 6; ++tI) {
        const int c = cell[tI];
        if (c < 169) {
            float m = -INFINITY;
#pragma unroll
            for (int k = 0; k < 9; ++k)
                m = fmaxf(m, gelu_exact(acc[tI][k] + bias));
            const int cy = c / 13, cx = c % 13;
            s2[((img * 32 + cog * 8 + co) * 13 + cy) * 13 + cx] = m;
        }
    }
}

// ---------------- Kernel 3: conv3 + GELU + pool3 ----------------
// grid = NIMG, block = 256
// out layout: [img][co*9 + py*3 + px]
__global__ __launch_bounds__(256) void k3_conv(const float* __restrict__ s2,
                                               const float* __restrict__ w3,
                                               const float* __restrict__ b3,
                                               float* __restrict__ out) {
    const int img = blockIdx.x;
    __shared__ float s2l[32 * 13 * 13];      // 5408 floats
    __shared__ float wl[32 * 32 * 9];        // 9216 floats

    const int tid = threadIdx.x;
    for (int i = tid; i < 32 * 13 * 13; i += 256) s2l[i] = s2[(size_t)img * 5408 + i];
    for (int i = tid; i < 32 * 32 * 9; i += 256) wl[i] = w3[i];
    __syncthreads();

    for (int task = tid; task < 288; task += 256) {
        const int co   = task / 9;
        const int cellid = task % 9;
        const int cy = cellid / 3, cx = cellid % 3;
        const int base = (3 * cy) * 13 + 3 * cx;

        float acc[9];
#pragma unroll
        for (int k = 0; k < 9; ++k) acc[k] = 0.f;

        for (int cin = 0; cin < 32; ++cin) {
            float w[9];
#pragma unroll
            for (int k = 0; k < 9; ++k) w[k] = wl[(co * 32 + cin) * 9 + k];
            float win[5][5];
#pragma unroll
            for (int r = 0; r < 5; ++r)
#pragma unroll
                for (int c2 = 0; c2 < 5; ++c2)
                    win[r][c2] = s2l[cin * 169 + base + r * 13 + c2];
#pragma unroll
            for (int wy = 0; wy < 3; ++wy)
#pragma unroll
                for (int wx = 0; wx < 3; ++wx)
#pragma unroll
                    for (int dy = 0; dy < 3; ++dy)
#pragma unroll
                        for (int dx = 0; dx < 3; ++dx)
                            acc[wy * 3 + wx] += win[wy + dy][wx + dx] * w[dy * 3 + dx];
        }

        const float bias = b3[co];
        float m = -INFINITY;
#pragma unroll
        for (int k = 0; k < 9; ++k)
            m = fmaxf(m, gelu_exact(acc[k] + bias));
        out[(size_t)img * 288 + task] = m;
    }
}

extern "C" void kernel_launch(void* const* d_in, const int* in_sizes, int n_in,
                              void* d_out, int out_size, void* d_ws, size_t ws_size,
                              hipStream_t stream) {
    const float* tok = (const float*)d_in[0];   // token_features (B,S,D) -> width axis
    const float* typ = (const float*)d_in[1];   // type_embedds  (B,S,D) -> height axis
    const float* w1  = (const float*)d_in[2];
    const float* b1  = (const float*)d_in[3];
    const float* w2  = (const float*)d_in[4];
    const float* b2  = (const float*)d_in[5];
    const float* w3  = (const float*)d_in[6];
    const float* b3  = (const float*)d_in[7];
    float* out = (float*)d_out;

    // workspace: s1 [512][16][42][42] fp32, then s2 [512][32][13][13] fp32
    float* s1 = (float*)d_ws;
    float* s2 = s1 + (size_t)NIMG * 16 * 42 * 42;   // 14,450,688 floats = 57.8 MB

    k1_fused<<<dim3(NIMG * 4), dim3(256), 0, stream>>>(tok, typ, w1, b1, s1);
    k2_conv<<<dim3(NIMG * 4), dim3(256), 0, stream>>>(s1, w2, b2, s2);
    k3_conv<<<dim3(NIMG), dim3(256), 0, stream>>>(s2, w3, b3, out);
}

// Round 2
// 296.131 us; speedup vs baseline: 1.5443x; 1.5443x over previous
//
#include <hip/hip_runtime.h>
#include <math.h>

// images: N = B*S = 512, each 256x256 = type[i] * token[j] (rank-1)
// stage1: conv 3x3 stride2 VALID (1->16ch) -> 127x127, GELU, pool3 -> 42x42
// stage2: conv 3x3 stride1 VALID (16->32)  -> 40x40,  GELU, pool3 -> 13x13
// stage3: conv 3x3 stride1 VALID (32->32)  -> 11x11,  GELU, pool3 -> 3x3
// out: [512][32*3*3=288] fp32

#define NIMG 512

__device__ __forceinline__ float gelu_exact(float x) {
    return 0.5f * x * (1.0f + erff(x * 0.70710678118654752f));
}

// GELU is valley-unimodal (decreasing on (-inf,-0.7518), increasing after).
// For any set S: max_{x in S} gelu(x) = max(gelu(min S), gelu(max S)).
// So maxpool(gelu(conv)) needs only min & max of the pre-activation window.
__device__ __forceinline__ float pool_gelu(float vmin, float vmax) {
    return fmaxf(gelu_exact(vmin), gelu_exact(vmax));
}

// ---------------- Kernel 1: outer-product + conv1(s2) + pool3 + GELU ----------------
// grid = NIMG*4 (4 channel-groups of 4 channels), block = 256
// s1 layout: [img][16][42][42]
__global__ __launch_bounds__(256) void k1_fused(const float* __restrict__ tok,
                                                const float* __restrict__ typ,
                                                const float* __restrict__ w1,
                                                const float* __restrict__ b1,
                                                float* __restrict__ s1) {
    const int blk = blockIdx.x;
    const int img = blk >> 2;
    const int cg  = blk & 3;                 // channels 4*cg .. 4*cg+3
    __shared__ float t[256];
    __shared__ float f[256];
    __shared__ float g[4][3][128];           // x in [0,126), padded

    const int tid = threadIdx.x;
    t[tid] = typ[img * 256 + tid];           // height axis = type_embedds
    f[tid] = tok[img * 256 + tid];           // width axis  = token_features
    __syncthreads();

    // g[c][di][x] = sum_dj w1[(4cg+c), di, dj] * f[2x+dj]
    for (int idx = tid; idx < 4 * 3 * 126; idx += 256) {
        const int x  = idx % 126;
        const int di = (idx / 126) % 3;
        const int c  = idx / (126 * 3);
        const int cc = cg * 4 + c;
        float acc = 0.f;
#pragma unroll
        for (int dj = 0; dj < 3; ++dj)
            acc += w1[cc * 9 + di * 3 + dj] * f[2 * x + dj];
        g[c][di][x] = acc;
    }
    __syncthreads();

    // pooled outputs: 4ch x 42 x 42; track window min/max of pre-activation
    for (int idx = tid; idx < 4 * 42 * 42; idx += 256) {
        const int px = idx % 42;
        const int py = (idx / 42) % 42;
        const int c  = idx / (42 * 42);
        const int cc = cg * 4 + c;
        float vmin = INFINITY, vmax = -INFINITY;
#pragma unroll
        for (int wy = 0; wy < 3; ++wy) {
            const int y = 3 * py + wy;
            const float t0 = t[2 * y], t1 = t[2 * y + 1], t2 = t[2 * y + 2];
#pragma unroll
            for (int wx = 0; wx < 3; ++wx) {
                const int x = 3 * px + wx;
                const float v = t0 * g[c][0][x] + t1 * g[c][1][x] + t2 * g[c][2][x];
                vmin = fminf(vmin, v);
                vmax = fmaxf(vmax, v);
            }
        }
        const float bias = b1[cc];
        s1[((img * 16 + cc) * 42 + py) * 42 + px] = pool_gelu(vmin + bias, vmax + bias);
    }
}

// ---------------- Kernel 2: conv2 + pool3 + GELU ----------------
// grid = NIMG*4 (4 co-groups of 8), block = 256.
// Each thread: 2 output channels x 3 pooled cells (column-major cell->lane map).
// s2 layout: [img][32][13][13]
__global__ __launch_bounds__(256) void k2_conv(const float* __restrict__ s1,
                                               const float* __restrict__ w2,
                                               const float* __restrict__ b2,
                                               float* __restrict__ s2) {
    const int blk = blockIdx.x;
    const int img = blk >> 2;
    const int cog = blk & 3;                 // co channels cog*8 .. cog*8+7
    __shared__ float4 slab4[441];            // one cin plane, 42*42 floats
    __shared__ float wl[8 * 16 * 9];
    float* slab = (float*)slab4;

    const int tid  = threadIdx.x;
    const int lane = tid & 63;
    const int grp  = tid >> 6;               // 0..3
    const int co_l0 = grp;                   // local co
    const int co_l1 = grp + 4;

    for (int i = tid; i < 8 * 16 * 9; i += 256) wl[i] = w2[cog * 8 * 16 * 9 + i];

    int base[3], valid[3], py[3], px[3];
#pragma unroll
    for (int tI = 0; tI < 3; ++tI) {
        const int c = lane + 64 * tI;        // pooled cell id, column-major
        valid[tI] = (c < 169);
        const int cc = valid[tI] ? c : 168;
        py[tI] = cc % 13;                    // consecutive lanes -> consecutive rows
        px[tI] = cc / 13;                    // (LDS stride 126 floats -> bank stride 30, <=2-way)
        base[tI] = py[tI] * 126 + px[tI] * 3;
    }

    float acc[2][3][9];
#pragma unroll
    for (int a = 0; a < 2; ++a)
#pragma unroll
        for (int tI = 0; tI < 3; ++tI)
#pragma unroll
            for (int k = 0; k < 9; ++k) acc[a][tI][k] = 0.f;

    const float* s1img = s1 + (size_t)img * 16 * 1764;

    for (int cin = 0; cin < 16; ++cin) {
        __syncthreads();                      // protect slab from previous iter
        const float4* src = (const float4*)(s1img + cin * 1764);
        for (int i = tid; i < 441; i += 256) slab4[i] = src[i];
        __syncthreads();

        float w0[9], w1r[9];
#pragma unroll
        for (int k = 0; k < 9; ++k) {
            w0[k]  = wl[(co_l0 * 16 + cin) * 9 + k];
            w1r[k] = wl[(co_l1 * 16 + cin) * 9 + k];
        }

#pragma unroll
        for (int tI = 0; tI < 3; ++tI) {
            float win[5][5];
#pragma unroll
            for (int r = 0; r < 5; ++r)
#pragma unroll
                for (int c2 = 0; c2 < 5; ++c2)
                    win[r][c2] = slab[base[tI] + r * 42 + c2];
#pragma unroll
            for (int wy = 0; wy < 3; ++wy)
#pragma unroll
                for (int wx = 0; wx < 3; ++wx) {
#pragma unroll
                    for (int dy = 0; dy < 3; ++dy)
#pragma unroll
                        for (int dx = 0; dx < 3; ++dx) {
                            const float v = win[wy + dy][wx + dx];
                            acc[0][tI][wy * 3 + wx] += v * w0[dy * 3 + dx];
                            acc[1][tI][wy * 3 + wx] += v * w1r[dy * 3 + dx];
                        }
                }
        }
    }

    const float b0 = b2[cog * 8 + co_l0];
    const float b1 = b2[cog * 8 + co_l1];
#pragma unroll
    for (int tI = 0; tI < 3; ++tI) {
        if (valid[tI]) {
#pragma unroll
            for (int a = 0; a < 2; ++a) {
                float vmin = INFINITY, vmax = -INFINITY;
#pragma unroll
                for (int k = 0; k < 9; ++k) {
                    vmin = fminf(vmin, acc[a][tI][k]);
                    vmax = fmaxf(vmax, acc[a][tI][k]);
                }
                const float bias = a ? b1 : b0;
                const int co = cog * 8 + (a ? co_l1 : co_l0);
                s2[((img * 32 + co) * 13 + py[tI]) * 13 + px[tI]] =
                    pool_gelu(vmin + bias, vmax + bias);
            }
        }
    }
}

// ---------------- Kernel 3: conv3 + pool3 + GELU ----------------
// grid = NIMG, block = 320 (5 waves), one (co,cell) task per thread, single pass.
// out layout: [img][co*9 + cy*3 + cx]
__global__ __launch_bounds__(320) void k3_conv(const float* __restrict__ s2,
                                               const float* __restrict__ w3,
                                               const float* __restrict__ b3,
                                               float* __restrict__ out) {
    const int img = blockIdx.x;
    __shared__ float4 s2l4[1352];            // 32*13*13 = 5408 floats
    __shared__ float4 wl4[2304];             // 32*32*9 = 9216 floats
    float* s2l = (float*)s2l4;
    float* wl  = (float*)wl4;

    const int tid = threadIdx.x;
    const float4* src = (const float4*)(s2 + (size_t)img * 5408);
    for (int i = tid; i < 1352; i += 320) s2l4[i] = src[i];
    const float4* wsrc = (const float4*)w3;
    for (int i = tid; i < 2304; i += 320) wl4[i] = wsrc[i];
    __syncthreads();

    if (tid < 288) {
        const int co   = tid / 9;
        const int cell = tid % 9;
        const int cy = cell / 3, cx = cell % 3;
        const int base = (3 * cy) * 13 + 3 * cx;

        float acc[9];
#pragma unroll
        for (int k = 0; k < 9; ++k) acc[k] = 0.f;

        for (int cin = 0; cin < 32; ++cin) {
            float w[9];
#pragma unroll
            for (int k = 0; k < 9; ++k) w[k] = wl[(co * 32 + cin) * 9 + k];
            float win[5][5];
#pragma unroll
            for (int r = 0; r < 5; ++r)
#pragma unroll
                for (int c2 = 0; c2 < 5; ++c2)
                    win[r][c2] = s2l[cin * 169 + base + r * 13 + c2];
#pragma unroll
            for (int wy = 0; wy < 3; ++wy)
#pragma unroll
                for (int wx = 0; wx < 3; ++wx)
#pragma unroll
                    for (int dy = 0; dy < 3; ++dy)
#pragma unroll
                        for (int dx = 0; dx < 3; ++dx)
                            acc[wy * 3 + wx] += win[wy + dy][wx + dx] * w[dy * 3 + dx];
        }

        float vmin = INFINITY, vmax = -INFINITY;
#pragma unroll
        for (int k = 0; k < 9; ++k) {
            vmin = fminf(vmin, acc[k]);
            vmax = fmaxf(vmax, acc[k]);
        }
        const float bias = b3[co];
        out[(size_t)img * 288 + tid] = pool_gelu(vmin + bias, vmax + bias);
    }
}

extern "C" void kernel_launch(void* const* d_in, const int* in_sizes, int n_in,
                              void* d_out, int out_size, void* d_ws, size_t ws_size,
                              hipStream_t stream) {
    const float* tok = (const float*)d_in[0];   // token_features (B,S,D) -> width axis
    const float* typ = (const float*)d_in[1];   // type_embedds  (B,S,D) -> height axis
    const float* w1  = (const float*)d_in[2];
    const float* b1  = (const float*)d_in[3];
    const float* w2  = (const float*)d_in[4];
    const float* b2  = (const float*)d_in[5];
    const float* w3  = (const float*)d_in[6];
    const float* b3  = (const float*)d_in[7];
    float* out = (float*)d_out;

    // workspace: s1 [512][16][42][42] fp32, then s2 [512][32][13][13] fp32
    float* s1 = (float*)d_ws;
    float* s2 = s1 + (size_t)NIMG * 16 * 42 * 42;   // 14,450,688 floats = 57.8 MB

    k1_fused<<<dim3(NIMG * 4), dim3(256), 0, stream>>>(tok, typ, w1, b1, s1);
    k2_conv<<<dim3(NIMG * 4), dim3(256), 0, stream>>>(s1, w2, b2, s2);
    k3_conv<<<dim3(NIMG), dim3(320), 0, stream>>>(s2, w3, b3, out);
}

// Round 3
// 259.767 us; speedup vs baseline: 1.7605x; 1.1400x over previous
//
#include <hip/hip_runtime.h>
#include <math.h>

// images: N = B*S = 512, each 256x256 = type[i] * token[j] (rank-1)
// stage1: conv 3x3 stride2 (1->16) -> 127x127, GELU, pool3 -> 42x42
// stage2: conv 3x3 stride1 (16->32) -> 40x40,  GELU, pool3 -> 13x13
// stage3: conv 3x3 stride1 (32->32) -> 11x11,  GELU, pool3 -> 3x3
// out: [512][288] fp32
//
// Key structural decisions (R3):
//  - GELU is valley-unimodal: maxpool(gelu(x)) = max(gelu(min x), gelu(max x)) -> 2 erf/cell.
//  - k1: conv1 input is rank-1; per-thread x-strip operands (g) live in VGPRs, t-reads are
//    wave-uniform scalar loads from global. NO LDS in the hot loop (was 36 reads/27 FMA).
//  - k2: 4 output channels per thread -> 13 FMA per ds_read; weights via readfirstlane ->
//    s_load into SGPRs (zero LDS weight traffic); slab padded [42][44] -> bank stride 4.
//  - k3: window read once per thread, shared across 2 co; ds_read imm offsets.

#define NIMG 512

__device__ __forceinline__ float gelu_exact(float x) {
    return 0.5f * x * (1.0f + erff(x * 0.70710678118654752f));
}
__device__ __forceinline__ float pool_gelu(float vmin, float vmax) {
    return fmaxf(gelu_exact(vmin), gelu_exact(vmax));
}

// ---------------- Kernel 1: outer-product + conv1(s2) + pool3 + GELU ----------------
// grid = NIMG*2 (py halves), block = 256 = 16 c x 16 pslot.
// Each thread owns 3 x-strips (px = pslot+16s) of one channel; sweeps 21 pooled rows.
// s1 layout: [img][16][42][44] (2-col pad for k2's float4 staging + bank stride)
__global__ __launch_bounds__(256) void k1_fused(const float* __restrict__ tok,
                                                const float* __restrict__ typ,
                                                const float* __restrict__ w1,
                                                const float* __restrict__ b1,
                                                float* __restrict__ s1) {
    const int blk = blockIdx.x;
    const int img = blk >> 1;
    const int py0 = (blk & 1) * 21;
    const int tid = threadIdx.x;
    const int c     = tid >> 4;
    const int pslot = tid & 15;

    float wv[9];
#pragma unroll
    for (int k = 0; k < 9; ++k) wv[k] = w1[c * 9 + k];
    const float bias = b1[c];

    const float* frow = tok + img * 256;   // width axis = token_features
    const float* trow = typ + img * 256;   // height axis = type_embedds

    // g[s][di][wx] = sum_dj w1[c,di,dj] * f[6*px+2*wx+dj]   (conv-x folded, stride 2)
    float g[3][3][3];
    int pxv[3];
#pragma unroll
    for (int s = 0; s < 3; ++s) {
        const int px = pslot + 16 * s;
        pxv[s] = px;
        const int pe = px < 42 ? px : 41;
        float f7[7];
#pragma unroll
        for (int q = 0; q < 7; ++q) f7[q] = frow[6 * pe + q];
#pragma unroll
        for (int di = 0; di < 3; ++di)
#pragma unroll
            for (int wx = 0; wx < 3; ++wx)
                g[s][di][wx] = wv[di * 3 + 0] * f7[2 * wx]
                             + wv[di * 3 + 1] * f7[2 * wx + 1]
                             + wv[di * 3 + 2] * f7[2 * wx + 2];
    }

    float* orow = s1 + ((size_t)img * 16 + c) * (42 * 44);
    for (int py = py0; py < py0 + 21; ++py) {
        float ts[7];                       // wave-uniform -> scalar loads
#pragma unroll
        for (int q = 0; q < 7; ++q) ts[q] = trow[6 * py + q];
#pragma unroll
        for (int s = 0; s < 3; ++s) {
            float vmin = INFINITY, vmax = -INFINITY;
#pragma unroll
            for (int wy = 0; wy < 3; ++wy) {
#pragma unroll
                for (int wx = 0; wx < 3; ++wx) {
                    float v = ts[2 * wy] * g[s][0][wx];
                    v = fmaf(ts[2 * wy + 1], g[s][1][wx], v);
                    v = fmaf(ts[2 * wy + 2], g[s][2][wx], v);
                    vmin = fminf(vmin, v);
                    vmax = fmaxf(vmax, v);
                }
            }
            if (pxv[s] < 42)
                orow[py * 44 + pxv[s]] = pool_gelu(vmin + bias, vmax + bias);
        }
    }
}

// ---------------- Kernel 2: conv2 + pool3 + GELU ----------------
// grid = NIMG*2 (cog of 16 co), block = 256. Each thread: 4 co x 3 pooled cells.
// Weights: wave-uniform -> SGPRs via readfirstlane (no LDS). s2: [img][32][13][13].
__global__ __launch_bounds__(256) void k2_conv(const float* __restrict__ s1,
                                               const float* __restrict__ w2,
                                               const float* __restrict__ b2,
                                               float* __restrict__ s2) {
    const int blk = blockIdx.x;
    const int img = blk >> 1;
    const int cog = blk & 1;               // co = cog*16 + grp + 4a
    __shared__ float4 slab4[462];          // [42][44] padded cin plane
    float* slab = (float*)slab4;

    const int tid  = threadIdx.x;
    const int lane = tid & 63;
    const int grp  = tid >> 6;             // wave id 0..3 (wave-uniform)

    int base[3], valid[3], py[3], px[3];
#pragma unroll
    for (int tI = 0; tI < 3; ++tI) {
        const int cc0 = lane + 64 * tI;    // col-major pooled cell id
        valid[tI] = (cc0 < 169);
        const int cc = valid[tI] ? cc0 : 168;
        py[tI] = cc % 13;                  // consecutive lanes -> consecutive rows
        px[tI] = cc / 13;
        base[tI] = py[tI] * 132 + px[tI] * 3;   // dword index: (3py)*44 + 3px
    }

    float acc[4][3][9];
#pragma unroll
    for (int a = 0; a < 4; ++a)
#pragma unroll
        for (int tI = 0; tI < 3; ++tI)
#pragma unroll
            for (int k = 0; k < 9; ++k) acc[a][tI][k] = 0.f;

    const float* s1img = s1 + (size_t)img * 16 * 1848;

    for (int cin = 0; cin < 16; ++cin) {
        __syncthreads();
        const float4* src = (const float4*)(s1img + cin * 1848);
        for (int i = tid; i < 462; i += 256) slab4[i] = src[i];
        __syncthreads();

        // weights -> SGPRs (uniform address)
        const int wbase = __builtin_amdgcn_readfirstlane((cog * 16 + grp) * 144 + cin * 9);
        float wv[4][9];
#pragma unroll
        for (int a = 0; a < 4; ++a)
#pragma unroll
            for (int k = 0; k < 9; ++k) wv[a][k] = w2[wbase + a * 576 + k];

#pragma unroll
        for (int tI = 0; tI < 3; ++tI) {
            float win[5][5];
#pragma unroll
            for (int r = 0; r < 5; ++r)
#pragma unroll
                for (int c2 = 0; c2 < 5; ++c2)
                    win[r][c2] = slab[base[tI] + r * 44 + c2];   // imm offsets
#pragma unroll
            for (int wy = 0; wy < 3; ++wy)
#pragma unroll
                for (int wx = 0; wx < 3; ++wx)
#pragma unroll
                    for (int dy = 0; dy < 3; ++dy)
#pragma unroll
                        for (int dx = 0; dx < 3; ++dx) {
                            const float v = win[wy + dy][wx + dx];
#pragma unroll
                            for (int a = 0; a < 4; ++a)
                                acc[a][tI][wy * 3 + wx] =
                                    fmaf(v, wv[a][dy * 3 + dx], acc[a][tI][wy * 3 + wx]);
                        }
        }
    }

#pragma unroll
    for (int tI = 0; tI < 3; ++tI) {
        if (valid[tI]) {
#pragma unroll
            for (int a = 0; a < 4; ++a) {
                float vmin = INFINITY, vmax = -INFINITY;
#pragma unroll
                for (int k = 0; k < 9; ++k) {
                    vmin = fminf(vmin, acc[a][tI][k]);
                    vmax = fmaxf(vmax, acc[a][tI][k]);
                }
                const int co = cog * 16 + grp + 4 * a;
                const float b = b2[co];
                s2[((img * 32 + co) * 13 + py[tI]) * 13 + px[tI]] =
                    pool_gelu(vmin + b, vmax + b);
            }
        }
    }
}

// ---------------- Kernel 3: conv3 + pool3 + GELU ----------------
// grid = NIMG, block = 192; 144 active tasks = (co-pair 0..15) x (cell 0..8).
// Window read once per thread per cin, shared across 2 co.
__global__ __launch_bounds__(192) void k3_conv(const float* __restrict__ s2,
                                               const float* __restrict__ w3,
                                               const float* __restrict__ b3,
                                               float* __restrict__ out) {
    const int img = blockIdx.x;
    __shared__ float4 s2l4[1352];          // 32*13*13 = 5408 floats
    __shared__ float wl[32 * 32 * 9];      // 9216 floats
    float* s2l = (float*)s2l4;

    const int tid = threadIdx.x;
    const float4* src = (const float4*)(s2 + (size_t)img * 5408);
    for (int i = tid; i < 1352; i += 192) s2l4[i] = src[i];
    for (int i = tid; i < 9216; i += 192) wl[i] = w3[i];
    __syncthreads();

    if (tid < 144) {
        const int cp   = tid / 9;          // co pair
        const int cell = tid % 9;
        const int cy = cell / 3, cx = cell % 3;
        const int base = (3 * cy) * 13 + 3 * cx;
        const int co0 = 2 * cp, co1 = 2 * cp + 1;

        float acc[2][9];
#pragma unroll
        for (int a = 0; a < 2; ++a)
#pragma unroll
            for (int k = 0; k < 9; ++k) acc[a][k] = 0.f;

        for (int cin = 0; cin < 32; ++cin) {
            float win[5][5];
#pragma unroll
            for (int r = 0; r < 5; ++r)
#pragma unroll
                for (int c2 = 0; c2 < 5; ++c2)
                    win[r][c2] = s2l[cin * 169 + base + r * 13 + c2];
            float wk[2][9];
#pragma unroll
            for (int k = 0; k < 9; ++k) {
                wk[0][k] = wl[(co0 * 32 + cin) * 9 + k];
                wk[1][k] = wl[(co1 * 32 + cin) * 9 + k];
            }
#pragma unroll
            for (int wy = 0; wy < 3; ++wy)
#pragma unroll
                for (int wx = 0; wx < 3; ++wx)
#pragma unroll
                    for (int dy = 0; dy < 3; ++dy)
#pragma unroll
                        for (int dx = 0; dx < 3; ++dx) {
                            const float v = win[wy + dy][wx + dx];
                            acc[0][wy * 3 + wx] = fmaf(v, wk[0][dy * 3 + dx], acc[0][wy * 3 + wx]);
                            acc[1][wy * 3 + wx] = fmaf(v, wk[1][dy * 3 + dx], acc[1][wy * 3 + wx]);
                        }
        }

#pragma unroll
        for (int a = 0; a < 2; ++a) {
            float vmin = INFINITY, vmax = -INFINITY;
#pragma unroll
            for (int k = 0; k < 9; ++k) {
                vmin = fminf(vmin, acc[a][k]);
                vmax = fmaxf(vmax, acc[a][k]);
            }
            const int co = a ? co1 : co0;
            const float b = b3[co];
            out[(size_t)img * 288 + co * 9 + cell] = pool_gelu(vmin + b, vmax + b);
        }
    }
}

extern "C" void kernel_launch(void* const* d_in, const int* in_sizes, int n_in,
                              void* d_out, int out_size, void* d_ws, size_t ws_size,
                              hipStream_t stream) {
    const float* tok = (const float*)d_in[0];
    const float* typ = (const float*)d_in[1];
    const float* w1  = (const float*)d_in[2];
    const float* b1  = (const float*)d_in[3];
    const float* w2  = (const float*)d_in[4];
    const float* b2  = (const float*)d_in[5];
    const float* w3  = (const float*)d_in[6];
    const float* b3  = (const float*)d_in[7];
    float* out = (float*)d_out;

    // ws: s1 [512][16][42][44] = 60.6 MB, s2 [512][32][13][13] = 11.1 MB
    float* s1 = (float*)d_ws;
    float* s2 = s1 + (size_t)NIMG * 16 * 42 * 44;

    k1_fused<<<dim3(NIMG * 2), dim3(256), 0, stream>>>(tok, typ, w1, b1, s1);
    k2_conv<<<dim3(NIMG * 2), dim3(256), 0, stream>>>(s1, w2, b2, s2);
    k3_conv<<<dim3(NIMG), dim3(192), 0, stream>>>(s2, w3, b3, out);
}

// Round 5
// 254.412 us; speedup vs baseline: 1.7975x; 1.0210x over previous
//
#include <hip/hip_runtime.h>
#include <math.h>

// images: N = B*S = 512, each 256x256 = type[i] * token[j] (rank-1)
// stage1: conv 3x3 stride2 (1->16) -> 127x127, GELU, pool3 -> 42x42
// stage2: conv 3x3 stride1 (16->32) -> 40x40,  GELU, pool3 -> 13x13
// stage3: conv 3x3 stride1 (32->32) -> 11x11,  GELU, pool3 -> 3x3
// out: [512][288] fp32
//
// R4 structure (resubmitted R5 — R4 bench timed out, kernel unmeasured):
//  - GELU valley-unimodal: maxpool(gelu(x)) = max(gelu(min x), gelu(max x)) -> 2 erf/cell.
//  - k1: rank-1 conv1 operands in VGPRs, wave-uniform scalar t-loads, no LDS.
//  - k2: row-major cell->lane map (bank stride 3, ~2-way = free);
//        global_load_lds width-16 double-buffered staging, 1 barrier/cin;
//        4 co x 3 cells per thread (13 FMA per ds_read); weights via s_load.
//  - k3: window shared across 2 co.

#define NIMG 512

__device__ __forceinline__ float gelu_exact(float x) {
    return 0.5f * x * (1.0f + erff(x * 0.70710678118654752f));
}
__device__ __forceinline__ float pool_gelu(float vmin, float vmax) {
    return fmaxf(gelu_exact(vmin), gelu_exact(vmax));
}

typedef __attribute__((address_space(3))) char lds_char;
typedef const __attribute__((address_space(1))) char glb_char;
__device__ __forceinline__ void gl_lds16(const void* g, void* l) {
    // async global->LDS, 16B per lane; LDS dest = wave-uniform base + lane*16
    __builtin_amdgcn_global_load_lds((glb_char*)g, (lds_char*)l, 16, 0, 0);
}

// ---------------- Kernel 1: outer-product + conv1(s2) + pool3 + GELU ----------------
// grid = NIMG*2 (py halves), block = 256 = 16 c x 16 pslot.
// s1 layout: [img][16][42][44]
__global__ __launch_bounds__(256) void k1_fused(const float* __restrict__ tok,
                                                const float* __restrict__ typ,
                                                const float* __restrict__ w1,
                                                const float* __restrict__ b1,
                                                float* __restrict__ s1) {
    const int blk = blockIdx.x;
    const int img = blk >> 1;
    const int py0 = (blk & 1) * 21;
    const int tid = threadIdx.x;
    const int c     = tid >> 4;
    const int pslot = tid & 15;

    float wv[9];
#pragma unroll
    for (int k = 0; k < 9; ++k) wv[k] = w1[c * 9 + k];
    const float bias = b1[c];

    const float* frow = tok + img * 256;   // width axis = token_features
    const float* trow = typ + img * 256;   // height axis = type_embedds

    float g[3][3][3];
    int pxv[3];
#pragma unroll
    for (int s = 0; s < 3; ++s) {
        const int px = pslot + 16 * s;
        pxv[s] = px;
        const int pe = px < 42 ? px : 41;
        float f7[7];
#pragma unroll
        for (int q = 0; q < 7; ++q) f7[q] = frow[6 * pe + q];
#pragma unroll
        for (int di = 0; di < 3; ++di)
#pragma unroll
            for (int wx = 0; wx < 3; ++wx)
                g[s][di][wx] = wv[di * 3 + 0] * f7[2 * wx]
                             + wv[di * 3 + 1] * f7[2 * wx + 1]
                             + wv[di * 3 + 2] * f7[2 * wx + 2];
    }

    float* orow = s1 + ((size_t)img * 16 + c) * (42 * 44);
    for (int py = py0; py < py0 + 21; ++py) {
        float ts[7];                       // wave-uniform -> scalar loads
#pragma unroll
        for (int q = 0; q < 7; ++q) ts[q] = trow[6 * py + q];
#pragma unroll
        for (int s = 0; s < 3; ++s) {
            float vmin = INFINITY, vmax = -INFINITY;
#pragma unroll
            for (int wy = 0; wy < 3; ++wy) {
#pragma unroll
                for (int wx = 0; wx < 3; ++wx) {
                    float v = ts[2 * wy] * g[s][0][wx];
                    v = fmaf(ts[2 * wy + 1], g[s][1][wx], v);
                    v = fmaf(ts[2 * wy + 2], g[s][2][wx], v);
                    vmin = fminf(vmin, v);
                    vmax = fmaxf(vmax, v);
                }
            }
            if (pxv[s] < 42)
                orow[py * 44 + pxv[s]] = pool_gelu(vmin + bias, vmax + bias);
        }
    }
}

// ---------------- Kernel 2: conv2 + pool3 + GELU ----------------
// grid = NIMG*2 (cog of 16 co), block = 256. Each thread: 4 co x 3 pooled cells.
// s2 layout: [img][32][13][13]
__global__ __launch_bounds__(256) void k2_conv(const float* __restrict__ s1,
                                               const float* __restrict__ w2,
                                               const float* __restrict__ b2,
                                               float* __restrict__ s2) {
    const int blk = blockIdx.x;
    const int img = blk >> 1;
    const int cog = blk & 1;               // co = cog*16 + grp + 4a
    __shared__ float4 slab4[2][512];       // double-buffered [42][44] plane (+pad)

    const int tid  = threadIdx.x;
    const int lane = tid & 63;
    const int grp  = tid >> 6;             // wave id 0..3 (wave-uniform)
    const int wbase64 = tid & ~63;         // wave-uniform lane base

    int base[3], valid[3], py[3], px[3];
#pragma unroll
    for (int tI = 0; tI < 3; ++tI) {
        const int cc0 = lane + 64 * tI;    // ROW-major pooled cell id
        valid[tI] = (cc0 < 169);
        const int cc = valid[tI] ? cc0 : 168;
        py[tI] = cc / 13;
        px[tI] = cc % 13;                  // consecutive lanes -> consecutive cols
        base[tI] = py[tI] * 132 + px[tI] * 3;   // (3py)*44 + 3px  (bank stride 3)
    }

    float acc[4][3][9];
#pragma unroll
    for (int a = 0; a < 4; ++a)
#pragma unroll
        for (int tI = 0; tI < 3; ++tI)
#pragma unroll
            for (int k = 0; k < 9; ++k) acc[a][tI][k] = 0.f;

    const float* s1img = s1 + (size_t)img * 16 * 1848;

    // prologue: stage plane 0 into buf 0
    {
        const char* src = (const char*)(s1img);
        gl_lds16(src + (size_t)tid * 16,        (char*)&slab4[0][0] + (size_t)wbase64 * 16);
        gl_lds16(src + (size_t)(256 + tid) * 16,(char*)&slab4[0][256] + (size_t)wbase64 * 16);
    }
    asm volatile("s_waitcnt vmcnt(0)" ::: "memory");
    __syncthreads();

#pragma unroll 1
    for (int cin = 0; cin < 16; ++cin) {
        const int cur = cin & 1;
        // issue next plane's loads (async; lands during compute)
        if (cin < 15) {
            const char* src = (const char*)(s1img + (cin + 1) * 1848);
            gl_lds16(src + (size_t)tid * 16,         (char*)&slab4[cur ^ 1][0] + (size_t)wbase64 * 16);
            gl_lds16(src + (size_t)(256 + tid) * 16, (char*)&slab4[cur ^ 1][256] + (size_t)wbase64 * 16);
        }

        // weights -> SGPRs (uniform address)
        const int wb = __builtin_amdgcn_readfirstlane((cog * 16 + grp) * 144 + cin * 9);
        float wv[4][9];
#pragma unroll
        for (int a = 0; a < 4; ++a)
#pragma unroll
            for (int k = 0; k < 9; ++k) wv[a][k] = w2[wb + a * 576 + k];

        const float* slab = (const float*)&slab4[cur][0];
#pragma unroll
        for (int tI = 0; tI < 3; ++tI) {
            float win[5][5];
#pragma unroll
            for (int r = 0; r < 5; ++r)
#pragma unroll
                for (int c2 = 0; c2 < 5; ++c2)
                    win[r][c2] = slab[base[tI] + r * 44 + c2];   // imm offsets
#pragma unroll
            for (int wy = 0; wy < 3; ++wy)
#pragma unroll
                for (int wx = 0; wx < 3; ++wx)
#pragma unroll
                    for (int dy = 0; dy < 3; ++dy)
#pragma unroll
                        for (int dx = 0; dx < 3; ++dx) {
                            const float v = win[wy + dy][wx + dx];
#pragma unroll
                            for (int a = 0; a < 4; ++a)
                                acc[a][tI][wy * 3 + wx] =
                                    fmaf(v, wv[a][dy * 3 + dx], acc[a][tI][wy * 3 + wx]);
                        }
        }

        // next buffer's loads landed + everyone done reading cur
        asm volatile("s_waitcnt vmcnt(0)" ::: "memory");
        __syncthreads();
    }

#pragma unroll
    for (int tI = 0; tI < 3; ++tI) {
        if (valid[tI]) {
#pragma unroll
            for (int a = 0; a < 4; ++a) {
                float vmin = INFINITY, vmax = -INFINITY;
#pragma unroll
                for (int k = 0; k < 9; ++k) {
                    vmin = fminf(vmin, acc[a][tI][k]);
                    vmax = fmaxf(vmax, acc[a][tI][k]);
                }
                const int co = cog * 16 + grp + 4 * a;
                const float b = b2[co];
                s2[((img * 32 + co) * 13 + py[tI]) * 13 + px[tI]] =
                    pool_gelu(vmin + b, vmax + b);
            }
        }
    }
}

// ---------------- Kernel 3: conv3 + pool3 + GELU ----------------
// grid = NIMG, block = 192; 144 active tasks = (co-pair) x (cell).
__global__ __launch_bounds__(192) void k3_conv(const float* __restrict__ s2,
                                               const float* __restrict__ w3,
                                               const float* __restrict__ b3,
                                               float* __restrict__ out) {
    const int img = blockIdx.x;
    __shared__ float4 s2l4[1352];          // 32*13*13 = 5408 floats
    __shared__ float wl[32 * 32 * 9];      // 9216 floats
    float* s2l = (float*)s2l4;

    const int tid = threadIdx.x;
    const float4* src = (const float4*)(s2 + (size_t)img * 5408);
    for (int i = tid; i < 1352; i += 192) s2l4[i] = src[i];
    for (int i = tid; i < 9216; i += 192) wl[i] = w3[i];
    __syncthreads();

    if (tid < 144) {
        const int cp   = tid / 9;          // co pair
        const int cell = tid % 9;
        const int cy = cell / 3, cx = cell % 3;
        const int base = (3 * cy) * 13 + 3 * cx;
        const int co0 = 2 * cp, co1 = 2 * cp + 1;

        float acc[2][9];
#pragma unroll
        for (int a = 0; a < 2; ++a)
#pragma unroll
            for (int k = 0; k < 9; ++k) acc[a][k] = 0.f;

        for (int cin = 0; cin < 32; ++cin) {
            float win[5][5];
#pragma unroll
            for (int r = 0; r < 5; ++r)
#pragma unroll
                for (int c2 = 0; c2 < 5; ++c2)
                    win[r][c2] = s2l[cin * 169 + base + r * 13 + c2];
            float wk[2][9];
#pragma unroll
            for (int k = 0; k < 9; ++k) {
                wk[0][k] = wl[(co0 * 32 + cin) * 9 + k];
                wk[1][k] = wl[(co1 * 32 + cin) * 9 + k];
            }
#pragma unroll
            for (int wy = 0; wy < 3; ++wy)
#pragma unroll
                for (int wx = 0; wx < 3; ++wx)
#pragma unroll
                    for (int dy = 0; dy < 3; ++dy)
#pragma unroll
                        for (int dx = 0; dx < 3; ++dx) {
                            const float v = win[wy + dy][wx + dx];
                            acc[0][wy * 3 + wx] = fmaf(v, wk[0][dy * 3 + dx], acc[0][wy * 3 + wx]);
                            acc[1][wy * 3 + wx] = fmaf(v, wk[1][dy * 3 + dx], acc[1][wy * 3 + wx]);
                        }
        }

#pragma unroll
        for (int a = 0; a < 2; ++a) {
            float vmin = INFINITY, vmax = -INFINITY;
#pragma unroll
            for (int k = 0; k < 9; ++k) {
                vmin = fminf(vmin, acc[a][k]);
                vmax = fmaxf(vmax, acc[a][k]);
            }
            const int co = a ? co1 : co0;
            const float b = b3[co];
            out[(size_t)img * 288 + co * 9 + cell] = pool_gelu(vmin + b, vmax + b);
        }
    }
}

extern "C" void kernel_launch(void* const* d_in, const int* in_sizes, int n_in,
                              void* d_out, int out_size, void* d_ws, size_t ws_size,
                              hipStream_t stream) {
    const float* tok = (const float*)d_in[0];
    const float* typ = (const float*)d_in[1];
    const float* w1  = (const float*)d_in[2];
    const float* b1  = (const float*)d_in[3];
    const float* w2  = (const float*)d_in[4];
    const float* b2  = (const float*)d_in[5];
    const float* w3  = (const float*)d_in[6];
    const float* b3  = (const float*)d_in[7];
    float* out = (float*)d_out;

    // ws: s1 [512][16][42][44] = 60.6 MB, then s2 [512][32][13][13] = 11.1 MB
    float* s1 = (float*)d_ws;
    float* s2 = s1 + (size_t)NIMG * 16 * 42 * 44;

    k1_fused<<<dim3(NIMG * 2), dim3(256), 0, stream>>>(tok, typ, w1, b1, s1);
    k2_conv<<<dim3(NIMG * 2), dim3(256), 0, stream>>>(s1, w2, b2, s2);
    k3_conv<<<dim3(NIMG), dim3(192), 0, stream>>>(s2, w3, b3, out);
}